// Round 11
// baseline (78.179 us; speedup 1.0000x reference)
//
#include <hip/hip_runtime.h>
#include <hip/hip_bf16.h>

typedef unsigned int u32;
typedef unsigned short u16;
typedef float f32x4 __attribute__((ext_vector_type(4)));
typedef short s16x8 __attribute__((ext_vector_type(8)));

#define B_   2
#define S_   2048
#define HID_ 512
#define H_   8
#define HKV_ 2
#define QB_  8
#define VB_  16
#define NQ_  64
#define HVB_ 128
#define LOG2E_ 1.4426950408889634f
#define MFIX2_ 24.525815695089866f   /* 17 * log2(e) */
#define PSLOT_ 544                   /* floats per partial slot: 512 O + 32 l */

// single-instruction RNE f32->bf16 (fptrunc) — bit-identical to manual round-to-
// nearest-even; proven passing r10.
__device__ __forceinline__ u16 bf16u(float f) {
    return __builtin_bit_cast(u16, (__bf16)f);
}
__device__ __forceinline__ f32x4 mfma16(s16x8 a, s16x8 b, f32x4 c) {
    return __builtin_amdgcn_mfma_f32_16x16x32_bf16(a, b, c, 0, 0, 0);
}
// NaN-free by range analysis: e in [0,inf] -> rcp in [0,1] -> result in [-1,1].
__device__ __forceinline__ float fast_tanh(float x) {
    float e = exp2f(x * (2.f * LOG2E_));
    return 1.f - 2.f * __builtin_amdgcn_rcpf(e + 1.f);
}
__device__ __forceinline__ float fast_sigmoid(float x) {
    return __builtin_amdgcn_rcpf(1.f + exp2f(-LOG2E_ * x));
}

// ------------------------------------------------- K0: weights -> single bf16 planes
// Wc [128][512] row-major (rows 112..127 zero-padded); Wob [512][128] row-major.
__global__ void k0_convert(const float* __restrict__ Wq, const float* __restrict__ Wk,
                           const float* __restrict__ Wv, const float* __restrict__ Wo,
                           u16* __restrict__ Wc, u16* __restrict__ Wob) {
    int idx = blockIdx.x * 256 + threadIdx.x;          // grid 256 -> 65536 threads
    {
        int n = idx >> 9, k = idx & 511;
        float v = (n < NQ_) ? Wq[n * HID_ + k]
                : (n < NQ_ + 16) ? Wk[(n - NQ_) * HID_ + k]
                : (n < 112) ? Wv[(n - NQ_ - 16) * HID_ + k] : 0.f;
        Wc[idx] = bf16u(v);                            // idx == n*512 + k
    }
    Wob[idx] = bf16u(Wo[idx]);                         // 512*128 == 65536
}

// ------------------------------------------------- K1: projections (single bf16, no LDS)
// grid 512 = 256 row-tiles x 2 halves; block 256 (4 waves); wave owns ONE n-frag.
// q is PRE-SCALED by log2(e)/16 so k2's scores are directly in exp2 domain.
__global__ __launch_bounds__(256) void k1_proj(
    const float* __restrict__ hidden, const u16* __restrict__ Wc,
    u16* __restrict__ qb, u16* __restrict__ kb, u16* __restrict__ vt)
{
    const int tid = threadIdx.x;
    const int r0 = (int)(blockIdx.x >> 1) * 16;
    const int wv = tid >> 6, lane = tid & 63;
    const int li = lane & 15, lo4 = lane >> 4;
    const int fr = (blockIdx.x & 1) * 4 + wv;
    if (fr >= 7) return;                               // 112 cols = 7 frags
    const int n = fr * 16 + li;

    const float* hrow = hidden + (r0 + li) * HID_;
    f32x4 acc = (f32x4){0.f, 0.f, 0.f, 0.f};

    #pragma unroll
    for (int kc = 0; kc < 16; ++kc) {
        f32x4 x0 = *(const f32x4*)&hrow[32 * kc + 8 * lo4];
        f32x4 x1 = *(const f32x4*)&hrow[32 * kc + 8 * lo4 + 4];
        s16x8 a = { (short)bf16u(x0[0]), (short)bf16u(x0[1]), (short)bf16u(x0[2]), (short)bf16u(x0[3]),
                    (short)bf16u(x1[0]), (short)bf16u(x1[1]), (short)bf16u(x1[2]), (short)bf16u(x1[3]) };
        s16x8 bfr = *(const s16x8*)&Wc[n * HID_ + 32 * kc + 8 * lo4];
        acc = mfma16(a, bfr, acc);
    }

    // wave-uniform destination branch (frag 0-3 -> q, 4 -> k, 5-6 -> v)
    #pragma unroll
    for (int reg = 0; reg < 4; ++reg) {
        int gs = r0 + 4 * lo4 + reg;
        int b = gs >> 11, s = gs & 2047;
        float pre = acc[reg];
        if (n < NQ_) {
            int h = n >> 3, bit = n & 7;
            qb[(((b * H_ + h) * S_) + s) * QB_ + bit] =
                bf16u(fast_tanh(pre) * (0.0625f * LOG2E_));
        } else if (n < NQ_ + 16) {
            int nk = n - NQ_;
            kb[(((b * HKV_ + (nk >> 3)) * S_) + s) * QB_ + (nk & 7)] = bf16u(fast_tanh(pre));
        } else {
            int nv = n - NQ_ - 16;
            int hv = nv >> 4, vb = nv & 15;
            u16 sig = bf16u(fast_sigmoid(pre));
            if (s > 0)
                vt[((b * HKV_ + hv) * VB_ + vb) * S_ + (s - 1)] = sig;   // suffix shift
            if (s == S_ - 1)
                vt[((b * HKV_ + hv) * VB_ + vb) * S_ + (S_ - 1)] = 0;
        }
    }
}

// ------------------------------------------------- K2: fused windowed attention (partials)
// grid 2560 = 16 bh x 160 (r,c) work units. Row-block r (32 i-rows) has
// nJ = r/2+1 tiles, split into nc = ceil(nJ/8) chunks of <=8 tiles; block (r,c)
// handles chunk c with 4 waves, each wave <=2 tiles (uniform short chains — the
// r10 lesson: per-wave 8-tile serial chains caused a 42us drain tail).
// Partials (O,l) go to ws; k2b merges. Barrier-free main loop.
__global__ __launch_bounds__(256, 2) void k2_attn(
    const u16* __restrict__ qb, const u16* __restrict__ kb, const u16* __restrict__ vt,
    float* __restrict__ part)
{
    __shared__ __align__(16) u16 psa[4][32 * 72];      // per-wave P scratch
    __shared__ float Om[4][2][16][16];                 // [wave][ig][row][li]
    __shared__ float lv[4][2][16];

    const int bid = blockIdx.x;
    const int bh = bid & 15;
    const int wk = bid >> 4;                           // 0..159
    int r, c;
    if (wk < 16)      { r = wk;                    c = 0; }
    else if (wk < 48) { r = 16 + ((wk - 16) >> 1); c = (wk - 16) & 1; }
    else if (wk < 96) { r = 32 + (wk - 48) / 3;    c = (wk - 48) % 3; }
    else              { r = 48 + ((wk - 96) >> 2); c = (wk - 96) & 3; }

    const int I0 = r * 32;
    const int nJ = (r >> 1) + 1;
    const int b = bh >> 3, h = bh & 7, hkv = h >> 2;

    const int g = threadIdx.x >> 6;                    // wave 0..3
    const int lane = threadIdx.x & 63;
    const int li = lane & 15, lo4 = lane >> 4;

    u16* psw = psa[g];
    const u16* kpl = kb + ((b * HKV_ + hkv) * S_) * QB_ + (li + lo4 - 31) * QB_;
    const u16* vtp = vt + ((b * HKV_ + hkv) * VB_) * S_ + li * S_ + 8 * lo4;

    // 12 unique Q A-frags (sub-tile ig uses qfu[kk + 4*ig]; rows differ by 16 = 4 frag-steps)
    s16x8 qfu[12];
    {
        const int gr0 = I0 + li - 31 + lo4;
        const u16* qp = qb + ((b * H_ + h) * S_) * QB_ + gr0 * QB_;
        #pragma unroll
        for (int m = 0; m < 12; ++m) {
            s16x8 v = {0, 0, 0, 0, 0, 0, 0, 0};
            if (gr0 + 4 * m >= 0) v = *(const s16x8*)(qp + m * 32);
            qfu[m] = v;
        }
    }

    int ibase[2];
    float binv[2][4];
    #pragma unroll
    for (int ig = 0; ig < 2; ++ig) {
        ibase[ig] = I0 + 16 * ig + 4 * lo4;
        #pragma unroll
        for (int reg = 0; reg < 4; ++reg) {
            float d = (float)(ibase[ig] + reg + 1);
            float rc = __builtin_amdgcn_rcpf(d);
            rc = rc * (2.f - d * rc);                  // NR: f32-exact for our range
            binv[ig][reg] = rc * LOG2E_;
        }
    }

    f32x4 O[2];
    O[0] = (f32x4){0.f, 0.f, 0.f, 0.f};
    O[1] = (f32x4){0.f, 0.f, 0.f, 0.f};
    float lsum[2][4] = {{0.f, 0.f, 0.f, 0.f}, {0.f, 0.f, 0.f, 0.f}};

    #pragma unroll
    for (int t = 0; t < 2; ++t) {
        const int jt = 8 * c + g + 4 * t;
        if (jt < nJ) {
            const int J0 = jt * 64;

            // V frags (issue early; consumed after softmax)
            s16x8 vfr0 = *(const s16x8*)(vtp + J0);
            s16x8 vfr1 = *(const s16x8*)(vtp + J0 + 32);

            // QK^T: 20 dedup'd K loads in 5 chunks of 4 (low live set -> low VGPR
            // -> high TLP, the latency-hiding mechanism), 64 MFMAs.
            f32x4 sacc[2][4];
            #pragma unroll
            for (int ig = 0; ig < 2; ++ig)
                #pragma unroll
                for (int ns = 0; ns < 4; ++ns)
                    sacc[ig][ns] = (f32x4){0.f, 0.f, 0.f, 0.f};

            const u16* kt = kpl + jt * 512;
            if (jt == 0) {
                #pragma unroll
                for (int c5 = 0; c5 < 5; ++c5) {
                    s16x8 f[4];
                    #pragma unroll
                    for (int j = 0; j < 4; ++j) {
                        int m = 4 * c5 + j;
                        s16x8 v = {0, 0, 0, 0, 0, 0, 0, 0};
                        if (li + lo4 + 4 * m >= 31) v = *(const s16x8*)(kt + 32 * m);
                        f[j] = v;
                    }
                    #pragma unroll
                    for (int j = 0; j < 4; ++j) {
                        if (c5 < 4) {
                            sacc[0][c5] = mfma16(qfu[j],     f[j], sacc[0][c5]);
                            sacc[1][c5] = mfma16(qfu[j + 4], f[j], sacc[1][c5]);
                        }
                        if (c5 >= 1) {
                            sacc[0][c5 - 1] = mfma16(qfu[j + 4], f[j], sacc[0][c5 - 1]);
                            sacc[1][c5 - 1] = mfma16(qfu[j + 8], f[j], sacc[1][c5 - 1]);
                        }
                    }
                }
            } else {
                #pragma unroll
                for (int c5 = 0; c5 < 5; ++c5) {
                    s16x8 f[4];
                    #pragma unroll
                    for (int j = 0; j < 4; ++j)
                        f[j] = *(const s16x8*)(kt + 32 * (4 * c5 + j));
                    #pragma unroll
                    for (int j = 0; j < 4; ++j) {
                        if (c5 < 4) {
                            sacc[0][c5] = mfma16(qfu[j],     f[j], sacc[0][c5]);
                            sacc[1][c5] = mfma16(qfu[j + 4], f[j], sacc[1][c5]);
                        }
                        if (c5 >= 1) {
                            sacc[0][c5 - 1] = mfma16(qfu[j + 4], f[j], sacc[0][c5 - 1]);
                            sacc[1][c5 - 1] = mfma16(qfu[j + 8], f[j], sacc[1][c5 - 1]);
                        }
                    }
                }
            }

            // bias + strict mask + fixed-max exp2 (q pre-scaled by log2e/16)
            const float jlif = (float)(J0 + li);
            #pragma unroll
            for (int ig = 0; ig < 2; ++ig) {
                const bool edgev = (J0 + 63) >= (I0 + 16 * ig);   // wave-uniform
                #pragma unroll
                for (int reg = 0; reg < 4; ++reg) {
                    const int irow = ibase[ig] + reg;
                    const float bi = binv[ig][reg];
                    float p[4];
                    #pragma unroll
                    for (int ns = 0; ns < 4; ++ns) {
                        float bns = fmaf(jlif + (float)(16 * ns), bi, -MFIX2_);
                        float e = exp2f(sacc[ig][ns][reg] + bns);
                        if (edgev)
                            e = (J0 + 16 * ns + li < irow) ? e : 0.f;
                        p[ns] = e;
                    }
                    lsum[ig][reg] += (p[0] + p[1]) + (p[2] + p[3]);
                    #pragma unroll
                    for (int ns = 0; ns < 4; ++ns)
                        psw[(ig * 16 + 4 * lo4 + reg) * 72 + 16 * ns + li] = bf16u(p[ns]);
                }
            }

            // PV: P from per-wave LDS (same-wave ordering), V from regs
            #pragma unroll
            for (int ig = 0; ig < 2; ++ig) {
                s16x8 pa0 = *(const s16x8*)&psw[(ig * 16 + li) * 72 + 8 * lo4];
                s16x8 pa1 = *(const s16x8*)&psw[(ig * 16 + li) * 72 + 32 + 8 * lo4];
                O[ig] = mfma16(pa0, vfr0, O[ig]);
                O[ig] = mfma16(pa1, vfr1, O[ig]);
            }
        }
    }

    // cross-wave merge in LDS, then wave 0 writes the partial slot
    #pragma unroll
    for (int ig = 0; ig < 2; ++ig) {
        #pragma unroll
        for (int reg = 0; reg < 4; ++reg) {
            float l = lsum[ig][reg];
            l += __shfl_xor(l, 1);
            l += __shfl_xor(l, 2);
            l += __shfl_xor(l, 4);
            l += __shfl_xor(l, 8);
            Om[g][ig][4 * lo4 + reg][li] = O[ig][reg];
            if (li == 0) lv[g][ig][4 * lo4 + reg] = l;
        }
    }
    __syncthreads();

    if (g == 0) {
        float* ps = part + (size_t)((bh * 64 + r) * 4 + c) * PSLOT_;
        #pragma unroll
        for (int ig = 0; ig < 2; ++ig) {
            #pragma unroll
            for (int reg = 0; reg < 4; ++reg) {
                const int rw16 = 4 * lo4 + reg;
                const int row = 16 * ig + rw16;
                float Oc = (Om[0][ig][rw16][li] + Om[1][ig][rw16][li])
                         + (Om[2][ig][rw16][li] + Om[3][ig][rw16][li]);
                ps[row * 16 + li] = Oc;
                if (li == 0) {
                    float lc = (lv[0][ig][rw16] + lv[1][ig][rw16])
                             + (lv[2][ig][rw16] + lv[3][ig][rw16]);
                    ps[512 + row] = lc;
                }
            }
        }
    }
}

// ------------------------------------------------- K2b: merge partials -> AO (bf16)
// grid 1024 = 64 r x 16 bh; block 512: thread = (row, col) of the 32x16 tile.
__global__ __launch_bounds__(512) void k2b_merge(
    const float* __restrict__ part,
    const float* __restrict__ vemb0, const float* __restrict__ vemb1,
    u16* __restrict__ AO)
{
    const int bid = blockIdx.x;
    const int r = bid >> 4, bh = bid & 15;
    const int b = bh >> 3, h = bh & 7;
    const int nc = (r < 16) ? 1 : ((r >> 4) + 1);      // ceil(nJ/8)
    const int t = threadIdx.x;
    const int row = t >> 4, col = t & 15;

    const float* ps = part + (size_t)((bh * 64 + r) * 4) * PSLOT_;
    float Osum = 0.f, lsum = 0.f;
    for (int c = 0; c < nc; ++c) {
        Osum += ps[c * PSLOT_ + row * 16 + col];
        lsum += ps[c * PSLOT_ + 512 + row];
    }
    const int hc = h * VB_ + col;
    float e0 = vemb0[hc], e1 = vemb1[hc];
    float lr = fmaxf(lsum, 1e-30f);
    float rinv = __builtin_amdgcn_rcpf(lr);
    rinv = rinv * (2.f - lr * rinv);
    float o = Osum * rinv;
    const int s = r * 32 + row;
    AO[(b * S_ + s) * HVB_ + hc] = bf16u(e0 + o * (e1 - e0));
}

// ------------------------------------------------- K3: AO(bf16) @ Wo^T(bf16), no LDS
// grid 2048 = 256 row-tiles x 8 col-groups; block 256 (4 waves), wave owns 1 frag
__global__ __launch_bounds__(256) void k3_out(
    const u16* __restrict__ AO, const u16* __restrict__ Wob,
    float* __restrict__ out)
{
    const int tid = threadIdx.x;
    const int r0 = (int)(blockIdx.x >> 3) * 16;
    const int cg = blockIdx.x & 7;
    const int wv = tid >> 6, lane = tid & 63;
    const int li = lane & 15, lo4 = lane >> 4;
    const int o = cg * 64 + wv * 16 + li;

    const u16* arow = AO + (r0 + li) * HVB_;
    f32x4 acc = (f32x4){0.f, 0.f, 0.f, 0.f};

    #pragma unroll
    for (int kc = 0; kc < 4; ++kc) {
        s16x8 a = *(const s16x8*)&arow[32 * kc + 8 * lo4];
        s16x8 bfr = *(const s16x8*)&Wob[o * HVB_ + 32 * kc + 8 * lo4];
        acc = mfma16(a, bfr, acc);
    }

    #pragma unroll
    for (int reg = 0; reg < 4; ++reg)
        out[(r0 + 4 * lo4 + reg) * HID_ + o] = acc[reg];
}

// ------------------------------------------------- launch
extern "C" void kernel_launch(void* const* d_in, const int* in_sizes, int n_in,
                              void* d_out, int out_size, void* d_ws, size_t ws_size,
                              hipStream_t stream)
{
    (void)in_sizes; (void)n_in; (void)out_size;
    const float* hidden = (const float*)d_in[0];
    const float* Wq = (const float*)d_in[1];
    const float* Wk = (const float*)d_in[2];
    const float* Wv = (const float*)d_in[3];
    const float* Wo = (const float*)d_in[4];
    const float* ve0 = (const float*)d_in[5];
    const float* ve1 = (const float*)d_in[6];
    float* out = (float*)d_out;

    char* base = (char*)d_ws;
    u16* qb   = (u16*)(base);                       // [B,H,S,8]      524288 B (pre-scaled log2e/16)
    u16* kb   = (u16*)(base + 524288);              // [B,HKV,S,8]    131072 B
    u16* vt   = (u16*)(base + 655360);              // [B,HKV,16,S]   262144 B (shifted, transposed)
    u16* AO   = (u16*)(base + 917504);              // [B*S,128] bf16 1048576 B
    u16* Wc   = (u16*)(base + 1966080);             // [128,512] bf16  131072 B (padded)
    u16* Wob  = (u16*)(base + 2097152);             // [512,128] bf16  131072 B
    float* part = (float*)(base + 2228224);         // 4096 slots x 544 f = 8912896 B -> end 11141120
    if (ws_size < 11141120u) return;

    hipLaunchKernelGGL(k0_convert, dim3(256), dim3(256), 0, stream,
                       Wq, Wk, Wv, Wo, Wc, Wob);
    hipLaunchKernelGGL(k1_proj, dim3(512), dim3(256), 0, stream,
                       hidden, Wc, qb, kb, vt);
    hipLaunchKernelGGL(k2_attn, dim3(2560), dim3(256), 0, stream,
                       qb, kb, vt, part);
    hipLaunchKernelGGL(k2b_merge, dim3(1024), dim3(512), 0, stream,
                       part, ve0, ve1, AO);
    hipLaunchKernelGGL(k3_out, dim3(2048), dim3(256), 0, stream,
                       AO, Wob, out);
}

// Round 12
// 65.033 us; speedup vs baseline: 1.2022x; 1.2022x over previous
//
#include <hip/hip_runtime.h>
#include <hip/hip_bf16.h>

typedef unsigned int u32;
typedef unsigned short u16;
typedef float f32x4 __attribute__((ext_vector_type(4)));
typedef short s16x8 __attribute__((ext_vector_type(8)));

#define B_   2
#define S_   2048
#define HID_ 512
#define H_   8
#define HKV_ 2
#define QB_  8
#define VB_  16
#define NQ_  64
#define HVB_ 128
#define LOG2E_ 1.4426950408889634f
#define MFIX2_ 24.525815695089866f   /* 17 * log2(e) */

// single-instruction RNE f32->bf16 (fptrunc) — proven passing r10/r11.
__device__ __forceinline__ u16 bf16u(float f) {
    return __builtin_bit_cast(u16, (__bf16)f);
}
__device__ __forceinline__ f32x4 mfma16(s16x8 a, s16x8 b, f32x4 c) {
    return __builtin_amdgcn_mfma_f32_16x16x32_bf16(a, b, c, 0, 0, 0);
}
// NaN-free by range analysis: e in [0,inf] -> rcp in [0,1] -> result in [-1,1].
__device__ __forceinline__ float fast_tanh(float x) {
    float e = exp2f(x * (2.f * LOG2E_));
    return 1.f - 2.f * __builtin_amdgcn_rcpf(e + 1.f);
}
__device__ __forceinline__ float fast_sigmoid(float x) {
    return __builtin_amdgcn_rcpf(1.f + exp2f(-LOG2E_ * x));
}

// ------------------------------------------------- K0: weights -> single bf16 planes
__global__ void k0_convert(const float* __restrict__ Wq, const float* __restrict__ Wk,
                           const float* __restrict__ Wv, const float* __restrict__ Wo,
                           u16* __restrict__ Wc, u16* __restrict__ Wob) {
    int idx = blockIdx.x * 256 + threadIdx.x;          // grid 256 -> 65536 threads
    {
        int n = idx >> 9, k = idx & 511;
        float v = (n < NQ_) ? Wq[n * HID_ + k]
                : (n < NQ_ + 16) ? Wk[(n - NQ_) * HID_ + k]
                : (n < 112) ? Wv[(n - NQ_ - 16) * HID_ + k] : 0.f;
        Wc[idx] = bf16u(v);                            // idx == n*512 + k
    }
    Wob[idx] = bf16u(Wo[idx]);                         // 512*128 == 65536
}

// ------------------------------------------------- K1: projections (single bf16, no LDS)
// grid 256 (16 rows), block 256 (4 waves); wave wv owns n-frags {wv, wv+4}.
// q PRE-SCALED by log2(e)/16 -> k2 scores directly in exp2 domain.
__global__ __launch_bounds__(256) void k1_proj(
    const float* __restrict__ hidden, const u16* __restrict__ Wc,
    u16* __restrict__ qb, u16* __restrict__ kb, u16* __restrict__ vt)
{
    const int tid = threadIdx.x;
    const int r0 = blockIdx.x * 16;
    const int wv = tid >> 6, lane = tid & 63;
    const int li = lane & 15, lo4 = lane >> 4;

    const float* hrow = hidden + (r0 + li) * HID_;

    f32x4 acc[2];
    acc[0] = (f32x4){0.f, 0.f, 0.f, 0.f};
    acc[1] = (f32x4){0.f, 0.f, 0.f, 0.f};

    #pragma unroll
    for (int kc = 0; kc < 16; ++kc) {
        f32x4 x0 = *(const f32x4*)&hrow[32 * kc + 8 * lo4];
        f32x4 x1 = *(const f32x4*)&hrow[32 * kc + 8 * lo4 + 4];
        s16x8 a = { (short)bf16u(x0[0]), (short)bf16u(x0[1]), (short)bf16u(x0[2]), (short)bf16u(x0[3]),
                    (short)bf16u(x1[0]), (short)bf16u(x1[1]), (short)bf16u(x1[2]), (short)bf16u(x1[3]) };
        #pragma unroll
        for (int u = 0; u < 2; ++u) {
            int n = (wv + 4 * u) * 16 + li;
            s16x8 bfr = *(const s16x8*)&Wc[n * HID_ + 32 * kc + 8 * lo4];
            acc[u] = mfma16(a, bfr, acc[u]);
        }
    }

    #pragma unroll
    for (int u = 0; u < 2; ++u) {
        int n = (wv + 4 * u) * 16 + li;
        if (n < 112) {
            #pragma unroll
            for (int reg = 0; reg < 4; ++reg) {
                int gs = r0 + 4 * lo4 + reg;
                int b = gs >> 11, s = gs & 2047;
                float pre = acc[u][reg];
                if (n < NQ_) {
                    int h = n >> 3, bit = n & 7;
                    qb[(((b * H_ + h) * S_) + s) * QB_ + bit] =
                        bf16u(fast_tanh(pre) * (0.0625f * LOG2E_));
                } else if (n < NQ_ + 16) {
                    int nk = n - NQ_;
                    kb[(((b * HKV_ + (nk >> 3)) * S_) + s) * QB_ + (nk & 7)] = bf16u(fast_tanh(pre));
                } else {
                    int nv = n - NQ_ - 16;
                    int hv = nv >> 4, vb = nv & 15;
                    u16 sig = bf16u(fast_sigmoid(pre));
                    if (s > 0)
                        vt[((b * HKV_ + hv) * VB_ + vb) * S_ + (s - 1)] = sig;   // suffix shift
                    if (s == S_ - 1)
                        vt[((b * HKV_ + hv) * VB_ + vb) * S_ + (S_ - 1)] = 0;
                }
            }
        }
    }
}

// ------------------------------------------------- K2: fused windowed attention
// grid 1024 = 64 row-blocks(32 i) x 16 bh; block 256 = 4 waves = 4 J-groups.
// Barrier-free main loop; flat ld[20] prefetch; hoisted LDS addresses (all
// P-write/read addrs loop-invariant -> ds imm offsets); incremental bias;
// ig-interleaved softmax/PV; s_setprio around MFMA clusters.
__global__ __launch_bounds__(256, 2) void k2_attn(
    const u16* __restrict__ qb, const u16* __restrict__ kb, const u16* __restrict__ vt,
    const float* __restrict__ vemb0, const float* __restrict__ vemb1,
    u16* __restrict__ AO)
{
    __shared__ __align__(16) u16 psa[4][32 * 72];      // per-wave P scratch
    __shared__ float Om[4][2][16][16];                 // [wave][ig][row][li]
    __shared__ float lv[4][2][16];

    const int bid = blockIdx.x;
    const int rb = bid >> 4;
    const int r  = (rb < 32) ? (63 - rb) : (rb - 32);  // heavy-first complementary pairing
    const int I0 = r * 32;
    const int nJ = ((I0 + 30) >> 6) + 1;               // j <= I0+30 needed
    const int bh = bid & 15;
    const int b = bh >> 3, h = bh & 7, hkv = h >> 2;

    const int g = threadIdx.x >> 6;                    // wave = J-group 0..3
    const int lane = threadIdx.x & 63;
    const int li = lane & 15, lo4 = lane >> 4;

    u16* psw = psa[g];
    const u16* kpl = kb + ((b * HKV_ + hkv) * S_) * QB_ + (li + lo4 - 31) * QB_;
    const u16* vtp = vt + ((b * HKV_ + hkv) * VB_) * S_ + li * S_ + 8 * lo4;

    // hoisted loop-invariant LDS addresses: 8 write bases (+imm 32*ns bytes), 2 read bases
    u16* wadr[2][4];
    const u16* radr[2];
    #pragma unroll
    for (int ig = 0; ig < 2; ++ig) {
        #pragma unroll
        for (int reg = 0; reg < 4; ++reg)
            wadr[ig][reg] = psw + (ig * 16 + 4 * lo4 + reg) * 72 + li;
        radr[ig] = psw + (ig * 16 + li) * 72 + 8 * lo4;
    }

    // 12 unique Q A-frags (ig uses qfu[kk + 4*ig]; sub-tiles 16 rows apart = 4 frag-steps)
    s16x8 qfu[12];
    {
        const int gr0 = I0 + li - 31 + lo4;
        const u16* qp = qb + ((b * H_ + h) * S_) * QB_ + gr0 * QB_;
        #pragma unroll
        for (int m = 0; m < 12; ++m) {
            s16x8 v = {0, 0, 0, 0, 0, 0, 0, 0};
            if (gr0 + 4 * m >= 0) v = *(const s16x8*)(qp + m * 32);
            qfu[m] = v;
        }
    }

    int ibase[2];
    float binv[2][4], bstep[2][4];
    #pragma unroll
    for (int ig = 0; ig < 2; ++ig) {
        ibase[ig] = I0 + 16 * ig + 4 * lo4;
        #pragma unroll
        for (int reg = 0; reg < 4; ++reg) {
            float d = (float)(ibase[ig] + reg + 1);
            float rc = __builtin_amdgcn_rcpf(d);
            rc = rc * (2.f - d * rc);                  // NR: f32-exact for our range
            binv[ig][reg] = rc * LOG2E_;
            bstep[ig][reg] = 16.f * rc * LOG2E_;
        }
    }

    f32x4 O[2];
    O[0] = (f32x4){0.f, 0.f, 0.f, 0.f};
    O[1] = (f32x4){0.f, 0.f, 0.f, 0.f};
    float lsum[2][4] = {{0.f, 0.f, 0.f, 0.f}, {0.f, 0.f, 0.f, 0.f}};

    // prologue: K loads for first tile (jt = g); g >= nJ waves read valid memory, unused.
    s16x8 ld[20];
    {
        const u16* kt = kpl + g * 512;
        if (g == 0) {
            #pragma unroll
            for (int m = 0; m < 20; ++m) {
                s16x8 v = {0, 0, 0, 0, 0, 0, 0, 0};
                if (li + lo4 + 4 * m >= 31) v = *(const s16x8*)(kt + 32 * m);
                ld[m] = v;
            }
        } else {
            #pragma unroll
            for (int m = 0; m < 20; ++m)
                ld[m] = *(const s16x8*)(kt + 32 * m);
        }
    }

    for (int jt = g; jt < nJ; jt += 4) {
        const int J0 = jt * 64;

        // V frags for THIS tile (consumed after softmax)
        s16x8 vfr0 = *(const s16x8*)(vtp + J0);
        s16x8 vfr1 = *(const s16x8*)(vtp + J0 + 32);

        // QK^T: 64 MFMAs off prefetched ld; frag(ig,ns,kk) = (qfu[kk+4ig], ld[4ns+kk])
        f32x4 sacc[2][4];
        #pragma unroll
        for (int ig = 0; ig < 2; ++ig)
            #pragma unroll
            for (int ns = 0; ns < 4; ++ns)
                sacc[ig][ns] = (f32x4){0.f, 0.f, 0.f, 0.f};
        __builtin_amdgcn_s_setprio(1);
        #pragma unroll
        for (int m = 0; m < 20; ++m) {
            s16x8 f = ld[m];
            {
                int kk = m & 3, ns = m >> 2;
                if (ns < 4) {
                    sacc[0][ns] = mfma16(qfu[kk],     f, sacc[0][ns]);
                    sacc[1][ns] = mfma16(qfu[kk + 4], f, sacc[1][ns]);
                }
            }
            {
                int kk = (m & 3) + 4, ns = (m >> 2) - 1;
                if (ns >= 0) {
                    sacc[0][ns] = mfma16(qfu[kk],     f, sacc[0][ns]);
                    sacc[1][ns] = mfma16(qfu[kk + 4], f, sacc[1][ns]);
                }
            }
        }
        __builtin_amdgcn_s_setprio(0);

        // prefetch NEXT tile's K (in flight during softmax+PV)
        if (jt + 4 < nJ) {
            const u16* kt = kpl + (jt + 4) * 512;
            #pragma unroll
            for (int m = 0; m < 20; ++m)
                ld[m] = *(const s16x8*)(kt + 32 * m);
        }

        // softmax(ig) then PV(ig) immediately — PV MFMAs overlap next ig's VALU
        const float jlif = (float)(J0 + li);
        #pragma unroll
        for (int ig = 0; ig < 2; ++ig) {
            const bool edgev = (J0 + 63) >= (I0 + 16 * ig);   // wave-uniform
            #pragma unroll
            for (int reg = 0; reg < 4; ++reg) {
                const int irow = ibase[ig] + reg;
                float bns = fmaf(jlif, binv[ig][reg], -MFIX2_);
                float p[4];
                #pragma unroll
                for (int ns = 0; ns < 4; ++ns) {
                    float e = exp2f(sacc[ig][ns][reg] + bns);
                    bns += bstep[ig][reg];
                    if (edgev)
                        e = (J0 + 16 * ns + li < irow) ? e : 0.f;
                    p[ns] = e;
                }
                lsum[ig][reg] += (p[0] + p[1]) + (p[2] + p[3]);
                wadr[ig][reg][0]  = bf16u(p[0]);
                wadr[ig][reg][16] = bf16u(p[1]);
                wadr[ig][reg][32] = bf16u(p[2]);
                wadr[ig][reg][48] = bf16u(p[3]);
            }
            s16x8 pa0 = *(const s16x8*)(radr[ig]);
            s16x8 pa1 = *(const s16x8*)(radr[ig] + 32);
            __builtin_amdgcn_s_setprio(1);
            O[ig] = mfma16(pa0, vfr0, O[ig]);
            O[ig] = mfma16(pa1, vfr1, O[ig]);
            __builtin_amdgcn_s_setprio(0);
        }
    }

    // publish partials (plain-sum merge: fixed max => no rescale)
    #pragma unroll
    for (int ig = 0; ig < 2; ++ig) {
        #pragma unroll
        for (int reg = 0; reg < 4; ++reg) {
            float l = lsum[ig][reg];
            l += __shfl_xor(l, 1);
            l += __shfl_xor(l, 2);
            l += __shfl_xor(l, 4);
            l += __shfl_xor(l, 8);
            Om[g][ig][4 * lo4 + reg][li] = O[ig][reg];
            if (li == 0) lv[g][ig][4 * lo4 + reg] = l;
        }
    }
    __syncthreads();

    if (g == 0) {
        const int hc = h * VB_ + li;
        const float e0 = vemb0[hc], e1 = vemb1[hc];
        #pragma unroll
        for (int ig = 0; ig < 2; ++ig) {
            #pragma unroll
            for (int reg = 0; reg < 4; ++reg) {
                const int row = 4 * lo4 + reg;
                float Oc = (Om[0][ig][row][li] + Om[1][ig][row][li])
                         + (Om[2][ig][row][li] + Om[3][ig][row][li]);
                float lc = (lv[0][ig][row] + lv[1][ig][row])
                         + (lv[2][ig][row] + lv[3][ig][row]);
                float lr = fmaxf(lc, 1e-30f);
                float rinv = __builtin_amdgcn_rcpf(lr);
                rinv = rinv * (2.f - lr * rinv);
                float o = Oc * rinv;
                const int s = I0 + 16 * ig + row;
                AO[(b * S_ + s) * HVB_ + hc] = bf16u(e0 + o * (e1 - e0));
            }
        }
    }
}

// ------------------------------------------------- K3: AO(bf16) @ Wo^T(bf16), no LDS
// grid 1024 = 256 row-tiles x 4 col-groups; block 256 (4 waves), wave owns 2 frags
__global__ __launch_bounds__(256) void k3_out(
    const u16* __restrict__ AO, const u16* __restrict__ Wob,
    float* __restrict__ out)
{
    const int tid = threadIdx.x;
    const int r0 = (int)(blockIdx.x >> 2) * 16;
    const int cg = blockIdx.x & 3;
    const int wv = tid >> 6, lane = tid & 63;
    const int li = lane & 15, lo4 = lane >> 4;

    const u16* arow = AO + (r0 + li) * HVB_;

    f32x4 acc[2];
    acc[0] = (f32x4){0.f, 0.f, 0.f, 0.f};
    acc[1] = (f32x4){0.f, 0.f, 0.f, 0.f};

    #pragma unroll
    for (int kc = 0; kc < 4; ++kc) {
        s16x8 a = *(const s16x8*)&arow[32 * kc + 8 * lo4];
        #pragma unroll
        for (int u = 0; u < 2; ++u) {
            int o = cg * 128 + (wv + 4 * u) * 16 + li;
            s16x8 bfr = *(const s16x8*)&Wob[o * HVB_ + 32 * kc + 8 * lo4];
            acc[u] = mfma16(a, bfr, acc[u]);
        }
    }

    #pragma unroll
    for (int u = 0; u < 2; ++u) {
        int o = cg * 128 + (wv + 4 * u) * 16 + li;
        #pragma unroll
        for (int reg = 0; reg < 4; ++reg)
            out[(r0 + 4 * lo4 + reg) * HID_ + o] = acc[u][reg];
    }
}

// ------------------------------------------------- launch
extern "C" void kernel_launch(void* const* d_in, const int* in_sizes, int n_in,
                              void* d_out, int out_size, void* d_ws, size_t ws_size,
                              hipStream_t stream)
{
    (void)in_sizes; (void)n_in; (void)out_size;
    const float* hidden = (const float*)d_in[0];
    const float* Wq = (const float*)d_in[1];
    const float* Wk = (const float*)d_in[2];
    const float* Wv = (const float*)d_in[3];
    const float* Wo = (const float*)d_in[4];
    const float* ve0 = (const float*)d_in[5];
    const float* ve1 = (const float*)d_in[6];
    float* out = (float*)d_out;

    char* base = (char*)d_ws;
    u16* qb  = (u16*)(base);                        // [B,H,S,8]      524288 B (pre-scaled log2e/16)
    u16* kb  = (u16*)(base + 524288);               // [B,HKV,S,8]    131072 B
    u16* vt  = (u16*)(base + 655360);               // [B,HKV,16,S]   262144 B (shifted, transposed)
    u16* AO  = (u16*)(base + 917504);               // [B*S,128] bf16 1048576 B
    u16* Wc  = (u16*)(base + 1966080);              // [128,512] bf16  131072 B (padded)
    u16* Wob = (u16*)(base + 2097152);              // [512,128] bf16  131072 B -> end 2228224
    if (ws_size < 2228224) return;

    hipLaunchKernelGGL(k0_convert, dim3(256), dim3(256), 0, stream,
                       Wq, Wk, Wv, Wo, Wc, Wob);
    hipLaunchKernelGGL(k1_proj, dim3(256), dim3(256), 0, stream,
                       hidden, Wc, qb, kb, vt);
    hipLaunchKernelGGL(k2_attn, dim3(1024), dim3(256), 0, stream,
                       qb, kb, vt, ve0, ve1, AO);
    hipLaunchKernelGGL(k3_out, dim3(1024), dim3(256), 0, stream,
                       AO, Wob, out);
}